// Round 1
// baseline (1062.783 us; speedup 1.0000x reference)
//
#include <hip/hip_runtime.h>
#include <math.h>

#define B_  32
#define M_  65536
#define W_  32
#define R_  4
#define K_  16
#define C_  65
#define IN_ 256

// ---------------- kernel 1: small matmuls + gather/update/scatter (in-place) ----------------
__global__ __launch_bounds__(256) void k_prep(
    const float* __restrict__ xi, float* __restrict__ memory,
    const float* __restrict__ read_weights, const float* __restrict__ write_weights,
    float* __restrict__ usage, const float* __restrict__ visible,
    const float* __restrict__ W_rq, const float* __restrict__ b_rq,
    const float* __restrict__ W_wv, const float* __restrict__ b_wv,
    const float* __restrict__ W_ig, const float* __restrict__ b_ig,
    const float* __restrict__ W_wg, const float* __restrict__ b_wg,
    const int* __restrict__ read_pos, const int* __restrict__ timestep_p,
    float* __restrict__ ws_rq)
{
    const int b = blockIdx.x, t = threadIdx.x;
    __shared__ __align__(16) float s_xi[IN_];
    __shared__ float s_wv[W_];
    __shared__ float s_ig[C_];
    __shared__ float s_wg;
    __shared__ float s_ru[C_], s_rwg[C_], s_u[C_];
    __shared__ float s_I[C_], s_wwnew[C_];
    __shared__ int   s_rp[C_];
    __shared__ unsigned char s_wok[C_];
    __shared__ float s_minu;

    s_xi[t] = xi[b * IN_ + t];
    __syncthreads();

    // 226 dot products: 128 rq, 32 wv, 65 ig, 1 wg
    if (t < 226) {
        const float* wrow; float bias;
        if (t < 128)      { wrow = W_rq + t * IN_;         bias = b_rq[t]; }
        else if (t < 160) { wrow = W_wv + (t - 128) * IN_; bias = b_wv[t - 128]; }
        else if (t < 225) { wrow = W_ig + (t - 160) * IN_; bias = b_ig[t - 160]; }
        else              { wrow = W_wg;                   bias = b_wg[0]; }
        float acc = 0.f;
        const float4* w4 = (const float4*)wrow;
        const float4* x4 = (const float4*)s_xi;
        #pragma unroll 4
        for (int q = 0; q < IN_ / 4; ++q) {
            float4 wv = w4[q]; float4 xv = x4[q];
            acc = fmaf(wv.x, xv.x, acc); acc = fmaf(wv.y, xv.y, acc);
            acc = fmaf(wv.z, xv.z, acc); acc = fmaf(wv.w, xv.w, acc);
        }
        acc += bias;
        if (t < 128)      ws_rq[b * 128 + t] = acc;
        else if (t < 160) s_wv[t - 128] = acc;
        else if (t < 225) s_ig[t - 160] = 1.f / (1.f + expf(-acc));
        else              s_wg = 1.f / (1.f + expf(-acc));
    }

    const int ts = timestep_p[0];
    if (t < C_) {
        int p = read_pos[b * C_ + t];
        s_rp[t] = p;
        float rwg = read_weights[(size_t)b * M_ + p];
        if (ts == 1) rwg += 1.0f;
        float wwg = write_weights[(size_t)b * M_ + p];
        s_rwg[t] = rwg;
        s_u[t]  = ((rwg + wwg) > 0.005f) ? 1.0f : 0.0f;
        s_ru[t] = usage[(size_t)b * M_ + p];
    }
    __syncthreads();
    if (t == 0) {
        float mn = s_ru[0];
        for (int c = 1; c < C_; ++c) mn = fminf(mn, s_ru[c]);
        s_minu = mn;
    }
    __syncthreads();
    if (t < C_) {
        float ru = s_ru[t];
        float I  = (ru == s_minu) ? 1.0f : 0.0f;
        float u  = s_u[t];
        float relnew = ((float)ts - ru) * u + ru * (1.0f - u);
        float ig = s_ig[t];
        float wwn = s_wg * (ig * s_rwg[t] + (1.0f - ig) * I);
        s_I[t] = I; s_wwnew[t] = wwn;
        usage[(size_t)b * M_ + s_rp[t]] = relnew;   // duplicates write identical values
        // last-c-wins for duplicate positions (numpy sequential-set semantics)
        unsigned char ok = 1;
        for (int c2 = t + 1; c2 < C_; ++c2) if (s_rp[c2] == s_rp[t]) { ok = 0; break; }
        s_wok[t] = ok;
    }
    __syncthreads();
    for (int i = t; i < C_ * W_; i += 256) {
        int c = i >> 5, w = i & 31;
        if (s_wok[c]) {
            float v = visible[((size_t)b * C_ + c) * W_ + w] * (1.0f - s_I[c]) + s_wwnew[c] * s_wv[w];
            memory[((size_t)b * M_ + s_rp[c]) * W_ + w] = v;
        }
    }
}

// ---------------- kernel 2: argmin partials over updated usage ----------------
__global__ __launch_bounds__(256) void k_argmin(
    const float* __restrict__ usage, float* __restrict__ pval, int* __restrict__ pidx)
{
    const int b = blockIdx.y, chunk = blockIdx.x, t = threadIdx.x;
    const float* u = usage + (size_t)b * M_ + chunk * 4096;
    float bv = 3.4e38f; int bi = 0x7fffffff;
    for (int i = t; i < 4096; i += 256) {      // per-thread indices ascend -> strict < keeps first
        float v = u[i];
        if (v < bv) { bv = v; bi = i; }
    }
    __shared__ float sv[256]; __shared__ int si[256];
    sv[t] = bv; si[t] = bi; __syncthreads();
    for (int s = 128; s > 0; s >>= 1) {
        if (t < s) {
            if (sv[t + s] < sv[t] || (sv[t + s] == sv[t] && si[t + s] < si[t])) {
                sv[t] = sv[t + s]; si[t] = si[t + s];
            }
        }
        __syncthreads();
    }
    if (t == 0) { pval[b * 16 + chunk] = sv[0]; pidx[b * 16 + chunk] = chunk * 4096 + si[0]; }
}

// ---------------- kernel 3: scores + per-wave exact top-16 (512 rows/wave) ----------------
__global__ __launch_bounds__(256) void k_scores(
    const float* __restrict__ memory, const float* __restrict__ ws_rq,
    float* __restrict__ cand_val, int* __restrict__ cand_idx)
{
    const int b = blockIdx.y, t = threadIdx.x;
    const int lane = t & 63, wid = t >> 6;
    __shared__ float s_rq[128];
    if (t < 128) s_rq[t] = ws_rq[b * 128 + t];
    __syncthreads();

    const int sub  = blockIdx.x * 4 + wid;   // [0,128)
    const int base = sub * 512;
    const float* mem_b = memory + (size_t)b * M_ * W_;

    float sc[8][4];
    #pragma unroll
    for (int s = 0; s < 8; ++s) {
        const int row = base + s * 64 + lane;
        const float4* m4 = (const float4*)(mem_b + (size_t)row * W_);
        float a0 = 0.f, a1 = 0.f, a2 = 0.f, a3 = 0.f;
        #pragma unroll
        for (int q = 0; q < 8; ++q) {
            float4 mv = m4[q];
            a0 = fmaf(mv.x, s_rq[      q*4+0], a0); a0 = fmaf(mv.y, s_rq[      q*4+1], a0);
            a0 = fmaf(mv.z, s_rq[      q*4+2], a0); a0 = fmaf(mv.w, s_rq[      q*4+3], a0);
            a1 = fmaf(mv.x, s_rq[ 32 + q*4+0], a1); a1 = fmaf(mv.y, s_rq[ 32 + q*4+1], a1);
            a1 = fmaf(mv.z, s_rq[ 32 + q*4+2], a1); a1 = fmaf(mv.w, s_rq[ 32 + q*4+3], a1);
            a2 = fmaf(mv.x, s_rq[ 64 + q*4+0], a2); a2 = fmaf(mv.y, s_rq[ 64 + q*4+1], a2);
            a2 = fmaf(mv.z, s_rq[ 64 + q*4+2], a2); a2 = fmaf(mv.w, s_rq[ 64 + q*4+3], a2);
            a3 = fmaf(mv.x, s_rq[ 96 + q*4+0], a3); a3 = fmaf(mv.y, s_rq[ 96 + q*4+1], a3);
            a3 = fmaf(mv.z, s_rq[ 96 + q*4+2], a3); a3 = fmaf(mv.w, s_rq[ 96 + q*4+3], a3);
        }
        sc[s][0] = a0; sc[s][1] = a1; sc[s][2] = a2; sc[s][3] = a3;
    }

    #pragma unroll
    for (int r = 0; r < 4; ++r) {
        float keep_v = 0.f; int keep_i = 0;
        for (int k = 0; k < 16; ++k) {
            float bv = sc[0][r]; int bs = 0;
            #pragma unroll
            for (int s = 1; s < 8; ++s) if (sc[s][r] > bv) { bv = sc[s][r]; bs = s; }
            int bi = base + bs * 64 + lane;
            // xor-butterfly argmax over 64 lanes; (val desc, idx asc) total order -> all lanes converge
            #pragma unroll
            for (int off = 32; off > 0; off >>= 1) {
                float ov = __shfl_xor(bv, off);
                int   oi = __shfl_xor(bi, off);
                if (ov > bv || (ov == bv && oi < bi)) { bv = ov; bi = oi; }
            }
            // mark the winner slot as consumed (only the owning lane can match d == s*64)
            int d = bi - base - lane;
            #pragma unroll
            for (int s = 0; s < 8; ++s) if (d == s * 64) sc[s][r] = -INFINITY;
            if (lane == k) { keep_v = bv; keep_i = bi; }
        }
        if (lane < 16) {
            int o = ((b * 4 + r) * 128 + sub) * 16 + lane;
            cand_val[o] = keep_v; cand_idx[o] = keep_i;
        }
    }
}

// ---------------- kernel 4: merge 128x16 candidates -> exact top-16 per (b,r) ----------------
__global__ __launch_bounds__(256) void k_merge(
    const float* __restrict__ cand_val, const int* __restrict__ cand_idx,
    int* __restrict__ ws_pos)
{
    const int br = blockIdx.x;           // b*4 + r
    const int b = br >> 2, r = br & 3;
    const int t = threadIdx.x, lane = t & 63, wid = t >> 6;
    __shared__ float s_val[2048];
    __shared__ int   s_idx[2048];
    __shared__ float s_wv[4]; __shared__ int s_wslot[4];
    __shared__ int   s_res[16];
    for (int i = t; i < 2048; i += 256) {
        s_val[i] = cand_val[br * 2048 + i];
        s_idx[i] = cand_idx[br * 2048 + i];
    }
    __syncthreads();
    for (int k = 0; k < 16; ++k) {
        float bv = s_val[t]; int bs = t;
        #pragma unroll
        for (int s = 1; s < 8; ++s) {
            float v = s_val[s * 256 + t];
            if (v > bv) { bv = v; bs = s * 256 + t; }
        }
        #pragma unroll
        for (int off = 32; off > 0; off >>= 1) {
            float ov = __shfl_xor(bv, off);
            int   os = __shfl_xor(bs, off);
            if (ov > bv || (ov == bv && os < bs)) { bv = ov; bs = os; }
        }
        if (lane == 0) { s_wv[wid] = bv; s_wslot[wid] = bs; }
        __syncthreads();
        if (t == 0) {
            float fv = s_wv[0]; int fs = s_wslot[0];
            #pragma unroll
            for (int w2 = 1; w2 < 4; ++w2)
                if (s_wv[w2] > fv || (s_wv[w2] == fv && s_wslot[w2] < fs)) { fv = s_wv[w2]; fs = s_wslot[w2]; }
            s_res[k] = s_idx[fs];
            s_val[fs] = -INFINITY;
        }
        __syncthreads();
    }
    if (t < 16) ws_pos[b * C_ + r * 16 + t] = s_res[t];
}

// ---------------- kernel 5: gather + cosine + softmax + weighted sum ----------------
__global__ __launch_bounds__(256) void k_final(
    const float* __restrict__ memory, const float* __restrict__ ws_rq,
    const float* __restrict__ amin_val, const int* __restrict__ amin_idx,
    const int* __restrict__ ws_pos, float* __restrict__ out)
{
    const int b = blockIdx.x, t = threadIdx.x;
    __shared__ int   s_pos[C_];
    __shared__ float s_vm[C_ * W_];
    __shared__ float s_rq[128];
    __shared__ float s_vnorm[C_], s_knorm[R_];
    __shared__ float s_a[R_ * C_];
    __shared__ float s_p[R_ * C_];

    if (t == 0) {   // reduce 16 argmin partials, first-index tie-break
        float bv = amin_val[b * 16]; int bi = amin_idx[b * 16];
        for (int i = 1; i < 16; ++i) {
            float v = amin_val[b * 16 + i]; int id = amin_idx[b * 16 + i];
            if (v < bv || (v == bv && id < bi)) { bv = v; bi = id; }
        }
        s_pos[64] = bi;
    }
    if (t < 64)  s_pos[t] = ws_pos[b * C_ + t];
    if (t < 128) s_rq[t] = ws_rq[b * 128 + t];
    __syncthreads();

    for (int i = t; i < C_ * W_; i += 256) {
        int c = i >> 5, w = i & 31;
        int p = s_pos[c]; p = p < 0 ? 0 : (p > M_ - 1 ? M_ - 1 : p);
        s_vm[i] = memory[((size_t)b * M_ + p) * W_ + w];
    }
    __syncthreads();
    if (t < C_) {
        float s = 0.f;
        for (int w = 0; w < W_; ++w) { float v = s_vm[t * W_ + w]; s = fmaf(v, v, s); }
        s_vnorm[t] = sqrtf(s) + 1e-6f;
    } else if (t < C_ + R_) {
        int r = t - C_;
        float s = 0.f;
        for (int w = 0; w < W_; ++w) { float v = s_rq[r * W_ + w]; s = fmaf(v, v, s); }
        s_knorm[r] = sqrtf(s) + 1e-6f;
    }
    __syncthreads();
    for (int i = t; i < R_ * C_; i += 256) {
        int r = i / C_, c = i % C_;
        float s = 0.f;
        for (int w = 0; w < W_; ++w) s = fmaf(s_vm[c * W_ + w], s_rq[r * W_ + w], s);
        s_a[i] = s / (32.0f * s_vnorm[c] * s_knorm[r] + 1e-6f);
    }
    __syncthreads();
    if (t < R_) {
        float mx = -INFINITY;
        for (int c = 0; c < C_; ++c) mx = fmaxf(mx, s_a[t * C_ + c]);
        float sum = 0.f;
        for (int c = 0; c < C_; ++c) { float e = expf(s_a[t * C_ + c] - mx); s_p[t * C_ + c] = e; sum += e; }
        float inv = 1.f / sum;
        for (int c = 0; c < C_; ++c) s_p[t * C_ + c] *= inv;
    }
    __syncthreads();
    if (t < 128) {
        int r = t >> 5, w = t & 31;
        float s = 0.f;
        for (int c = 0; c < C_; ++c) s = fmaf(s_p[r * C_ + c], s_vm[c * W_ + w], s);
        out[((size_t)b * R_ + r) * W_ + w] = s;
    }
}

extern "C" void kernel_launch(void* const* d_in, const int* in_sizes, int n_in,
                              void* d_out, int out_size, void* d_ws, size_t ws_size,
                              hipStream_t stream)
{
    const float* xi            = (const float*)d_in[0];
    float*       memory        = (float*)d_in[1];        // updated in place; harness restores inputs
    const float* read_weights  = (const float*)d_in[2];
    const float* write_weights = (const float*)d_in[3];
    float*       usage         = (float*)d_in[4];        // updated in place
    const float* visible       = (const float*)d_in[5];
    const float* W_rq = (const float*)d_in[6];
    const float* b_rq = (const float*)d_in[7];
    const float* W_wv = (const float*)d_in[8];
    const float* b_wv = (const float*)d_in[9];
    const float* W_ig = (const float*)d_in[10];
    const float* b_ig = (const float*)d_in[11];
    const float* W_wg = (const float*)d_in[12];
    const float* b_wg = (const float*)d_in[13];
    const int*   read_pos = (const int*)d_in[14];
    const int*   timestep = (const int*)d_in[16];
    float* out = (float*)d_out;
    (void)in_sizes; (void)n_in; (void)out_size; (void)ws_size;

    // workspace layout (~2.1 MB)
    float* ws_rq    = (float*)d_ws;                  // 32*128
    float* cand_val = ws_rq + 32 * 128;              // 32*4*128*16 = 262144
    int*   cand_idx = (int*)(cand_val + 262144);     // 262144
    float* amin_val = (float*)(cand_idx + 262144);   // 32*16
    int*   amin_idx = (int*)(amin_val + 512);        // 32*16
    int*   ws_pos   = amin_idx + 512;                // 32*65

    k_prep<<<dim3(32), dim3(256), 0, stream>>>(xi, memory, read_weights, write_weights,
        usage, visible, W_rq, b_rq, W_wv, b_wv, W_ig, b_ig, W_wg, b_wg,
        read_pos, timestep, ws_rq);
    k_argmin<<<dim3(16, 32), dim3(256), 0, stream>>>(usage, amin_val, amin_idx);
    k_scores<<<dim3(32, 32), dim3(256), 0, stream>>>(memory, ws_rq, cand_val, cand_idx);
    k_merge<<<dim3(128), dim3(256), 0, stream>>>(cand_val, cand_idx, ws_pos);
    k_final<<<dim3(32), dim3(256), 0, stream>>>(memory, ws_rq, amin_val, amin_idx, ws_pos, out);
}

// Round 2
// 693.719 us; speedup vs baseline: 1.5320x; 1.5320x over previous
//
#include <hip/hip_runtime.h>
#include <math.h>

#define B_  32
#define M_  65536
#define W_  32
#define R_  4
#define K_  16
#define C_  65
#define IN_ 256

// ---------------- kernel 1: small matmuls + gather/update/scatter (in-place) ----------------
__global__ __launch_bounds__(256) void k_prep(
    const float* __restrict__ xi, float* __restrict__ memory,
    const float* __restrict__ read_weights, const float* __restrict__ write_weights,
    float* __restrict__ usage, const float* __restrict__ visible,
    const float* __restrict__ W_rq, const float* __restrict__ b_rq,
    const float* __restrict__ W_wv, const float* __restrict__ b_wv,
    const float* __restrict__ W_ig, const float* __restrict__ b_ig,
    const float* __restrict__ W_wg, const float* __restrict__ b_wg,
    const int* __restrict__ read_pos, const int* __restrict__ timestep_p,
    float* __restrict__ ws_rq)
{
    const int b = blockIdx.x, t = threadIdx.x;
    __shared__ __align__(16) float s_xi[IN_];
    __shared__ float s_wv[W_];
    __shared__ float s_ig[C_];
    __shared__ float s_wg;
    __shared__ float s_ru[C_], s_rwg[C_], s_u[C_];
    __shared__ float s_I[C_], s_wwnew[C_];
    __shared__ int   s_rp[C_];
    __shared__ unsigned char s_wok[C_];
    __shared__ float s_minu;

    s_xi[t] = xi[b * IN_ + t];
    __syncthreads();

    // 226 dot products: 128 rq, 32 wv, 65 ig, 1 wg
    if (t < 226) {
        const float* wrow; float bias;
        if (t < 128)      { wrow = W_rq + t * IN_;         bias = b_rq[t]; }
        else if (t < 160) { wrow = W_wv + (t - 128) * IN_; bias = b_wv[t - 128]; }
        else if (t < 225) { wrow = W_ig + (t - 160) * IN_; bias = b_ig[t - 160]; }
        else              { wrow = W_wg;                   bias = b_wg[0]; }
        float acc = 0.f;
        const float4* w4 = (const float4*)wrow;
        const float4* x4 = (const float4*)s_xi;
        #pragma unroll 4
        for (int q = 0; q < IN_ / 4; ++q) {
            float4 wv = w4[q]; float4 xv = x4[q];
            acc = fmaf(wv.x, xv.x, acc); acc = fmaf(wv.y, xv.y, acc);
            acc = fmaf(wv.z, xv.z, acc); acc = fmaf(wv.w, xv.w, acc);
        }
        acc += bias;
        if (t < 128)      ws_rq[b * 128 + t] = acc;
        else if (t < 160) s_wv[t - 128] = acc;
        else if (t < 225) s_ig[t - 160] = 1.f / (1.f + expf(-acc));
        else              s_wg = 1.f / (1.f + expf(-acc));
    }

    const int ts = timestep_p[0];
    if (t < C_) {
        int p = read_pos[b * C_ + t];
        s_rp[t] = p;
        float rwg = read_weights[(size_t)b * M_ + p];
        if (ts == 1) rwg += 1.0f;
        float wwg = write_weights[(size_t)b * M_ + p];
        s_rwg[t] = rwg;
        s_u[t]  = ((rwg + wwg) > 0.005f) ? 1.0f : 0.0f;
        s_ru[t] = usage[(size_t)b * M_ + p];
    }
    __syncthreads();
    if (t == 0) {
        float mn = s_ru[0];
        for (int c = 1; c < C_; ++c) mn = fminf(mn, s_ru[c]);
        s_minu = mn;
    }
    __syncthreads();
    if (t < C_) {
        float ru = s_ru[t];
        float I  = (ru == s_minu) ? 1.0f : 0.0f;
        float u  = s_u[t];
        float relnew = ((float)ts - ru) * u + ru * (1.0f - u);
        float ig = s_ig[t];
        float wwn = s_wg * (ig * s_rwg[t] + (1.0f - ig) * I);
        s_I[t] = I; s_wwnew[t] = wwn;
        usage[(size_t)b * M_ + s_rp[t]] = relnew;   // duplicates write identical values
        // last-c-wins for duplicate positions (numpy sequential-set semantics)
        unsigned char ok = 1;
        for (int c2 = t + 1; c2 < C_; ++c2) if (s_rp[c2] == s_rp[t]) { ok = 0; break; }
        s_wok[t] = ok;
    }
    __syncthreads();
    for (int i = t; i < C_ * W_; i += 256) {
        int c = i >> 5, w = i & 31;
        if (s_wok[c]) {
            float v = visible[((size_t)b * C_ + c) * W_ + w] * (1.0f - s_I[c]) + s_wwnew[c] * s_wv[w];
            memory[((size_t)b * M_ + s_rp[c]) * W_ + w] = v;
        }
    }
}

// ---------------- kernel 2: argmin partials over updated usage ----------------
__global__ __launch_bounds__(256) void k_argmin(
    const float* __restrict__ usage, float* __restrict__ pval, int* __restrict__ pidx)
{
    const int b = blockIdx.y, chunk = blockIdx.x, t = threadIdx.x;
    const float* u = usage + (size_t)b * M_ + chunk * 4096;
    float bv = 3.4e38f; int bi = 0x7fffffff;
    for (int i = t; i < 4096; i += 256) {      // per-thread indices ascend -> strict < keeps first
        float v = u[i];
        if (v < bv) { bv = v; bi = i; }
    }
    __shared__ float sv[256]; __shared__ int si[256];
    sv[t] = bv; si[t] = bi; __syncthreads();
    for (int s = 128; s > 0; s >>= 1) {
        if (t < s) {
            if (sv[t + s] < sv[t] || (sv[t + s] == sv[t] && si[t + s] < si[t])) {
                sv[t] = sv[t + s]; si[t] = si[t + s];
            }
        }
        __syncthreads();
    }
    if (t == 0) { pval[b * 16 + chunk] = sv[0]; pidx[b * 16 + chunk] = chunk * 4096 + si[0]; }
}

// ---------------- kernel 3: pure streaming scores ----------------
// scores[b][r][M]; grid (64, 32): 1024 rows per block, 4 rows per thread
__global__ __launch_bounds__(256) void k_scores(
    const float* __restrict__ memory, const float* __restrict__ ws_rq,
    float* __restrict__ scores)
{
    const int b = blockIdx.y, t = threadIdx.x;
    __shared__ float s_rq[128];
    if (t < 128) s_rq[t] = ws_rq[b * 128 + t];
    __syncthreads();

    const float* mem_b = memory + (size_t)b * (M_ * W_);
    const int base = blockIdx.x * 1024;

    #pragma unroll
    for (int i = 0; i < 4; ++i) {
        const int row = base + i * 256 + t;
        const float4* m4 = (const float4*)(mem_b + (size_t)row * W_);
        float4 v[8];
        #pragma unroll
        for (int q = 0; q < 8; ++q) v[q] = m4[q];
        float a0 = 0.f, a1 = 0.f, a2 = 0.f, a3 = 0.f;
        #pragma unroll
        for (int q = 0; q < 8; ++q) {
            float4 mv = v[q];
            a0 = fmaf(mv.x, s_rq[      q*4+0], a0); a0 = fmaf(mv.y, s_rq[      q*4+1], a0);
            a0 = fmaf(mv.z, s_rq[      q*4+2], a0); a0 = fmaf(mv.w, s_rq[      q*4+3], a0);
            a1 = fmaf(mv.x, s_rq[ 32 + q*4+0], a1); a1 = fmaf(mv.y, s_rq[ 32 + q*4+1], a1);
            a1 = fmaf(mv.z, s_rq[ 32 + q*4+2], a1); a1 = fmaf(mv.w, s_rq[ 32 + q*4+3], a1);
            a2 = fmaf(mv.x, s_rq[ 64 + q*4+0], a2); a2 = fmaf(mv.y, s_rq[ 64 + q*4+1], a2);
            a2 = fmaf(mv.z, s_rq[ 64 + q*4+2], a2); a2 = fmaf(mv.w, s_rq[ 64 + q*4+3], a2);
            a3 = fmaf(mv.x, s_rq[ 96 + q*4+0], a3); a3 = fmaf(mv.y, s_rq[ 96 + q*4+1], a3);
            a3 = fmaf(mv.z, s_rq[ 96 + q*4+2], a3); a3 = fmaf(mv.w, s_rq[ 96 + q*4+3], a3);
        }
        const size_t o = ((size_t)(b * 4) << 16) + (size_t)row;
        scores[o]               = a0;
        scores[o + (1u << 16)]  = a1;
        scores[o + (2u << 16)]  = a2;
        scores[o + (3u << 16)]  = a3;
    }
}

// ---------------- kernel 4: exact top-16 per (b,r) via histogram select ----------------
__global__ __launch_bounds__(1024) void k_sel(
    const float* __restrict__ scores, int* __restrict__ ws_pos)
{
    const int br = blockIdx.x;               // b*4 + r, 128 blocks
    const int t  = threadIdx.x;
    const float* sc = scores + ((size_t)br << 16);

    __shared__ int   s_hist[4][2048];        // replicated to cut same-bin atomic serialization
    __shared__ int   s_sup[64];
    __shared__ int   s_T, s_cnt;
    __shared__ float c_val[2048];
    __shared__ int   c_idx[2048];
    __shared__ float r_val[1024];
    __shared__ int   r_idx[1024];
    __shared__ int   s_res[16];

    #pragma unroll
    for (int h = 0; h < 4; ++h) { s_hist[h][t] = 0; s_hist[h][t + 1024] = 0; }
    __syncthreads();

    const int hcopy = (t >> 8) & 3;
    // pass 1: histogram of monotone key's top 11 bits
    for (int i = 0; i < 64; ++i) {
        float v = sc[i * 1024 + t];
        unsigned ub = __float_as_uint(v);
        unsigned key = (ub & 0x80000000u) ? ~ub : (ub | 0x80000000u);
        atomicAdd(&s_hist[hcopy][key >> 21], 1);
    }
    __syncthreads();
    // merge replicas
    s_hist[0][t]        += s_hist[1][t]        + s_hist[2][t]        + s_hist[3][t];
    s_hist[0][t + 1024] += s_hist[1][t + 1024] + s_hist[2][t + 1024] + s_hist[3][t + 1024];
    __syncthreads();
    if (t < 64) {
        int s = 0;
        for (int j = 0; j < 32; ++j) s += s_hist[0][t * 32 + j];
        s_sup[t] = s;
    }
    __syncthreads();
    if (t == 0) {
        int cum = 0, sb = 63;
        for (; sb > 0; --sb) { cum += s_sup[sb]; if (cum >= 16) break; }
        if (cum < 16) { cum += s_sup[0]; sb = 0; }
        int above = cum - s_sup[sb];         // count in superbins > sb  (< 16)
        int T = sb * 32;
        for (int j = 31; j >= 0; --j) {
            above += s_hist[0][sb * 32 + j];
            if (above >= 16) { T = sb * 32 + j; break; }
        }
        s_T = T; s_cnt = 0;
    }
    __syncthreads();
    const unsigned T = (unsigned)s_T;
    // pass 2: compact candidates (bin >= T  =>  superset of exact top-16)
    for (int i = 0; i < 64; ++i) {
        int idx = i * 1024 + t;
        float v = sc[idx];
        unsigned ub = __float_as_uint(v);
        unsigned key = (ub & 0x80000000u) ? ~ub : (ub | 0x80000000u);
        if ((key >> 21) >= T) {
            int p = atomicAdd(&s_cnt, 1);
            if (p < 2048) { c_val[p] = v; c_idx[p] = idx; }
        }
    }
    __syncthreads();
    int n = s_cnt; if (n > 2048) n = 2048;
    // phase 3: 16 rounds of block argmax over candidates
    for (int k = 0; k < 16; ++k) {
        float bv = (t < n) ? c_val[t] : -INFINITY;
        int   bs = t;
        float v2 = (t + 1024 < n) ? c_val[t + 1024] : -INFINITY;
        if (v2 > bv) { bv = v2; bs = t + 1024; }
        r_val[t] = bv; r_idx[t] = bs;
        __syncthreads();
        for (int s = 512; s > 0; s >>= 1) {
            if (t < s) {
                if (r_val[t + s] > r_val[t]) { r_val[t] = r_val[t + s]; r_idx[t] = r_idx[t + s]; }
            }
            __syncthreads();
        }
        if (t == 0) {
            int slot = r_idx[0];
            s_res[k] = c_idx[slot];
            c_val[slot] = -INFINITY;
        }
        __syncthreads();
    }
    if (t < 16) {
        int b = br >> 2, r = br & 3;
        ws_pos[b * C_ + r * 16 + t] = s_res[t];
    }
}

// ---------------- kernel 5: gather + cosine + softmax + weighted sum ----------------
__global__ __launch_bounds__(256) void k_final(
    const float* __restrict__ memory, const float* __restrict__ ws_rq,
    const float* __restrict__ amin_val, const int* __restrict__ amin_idx,
    const int* __restrict__ ws_pos, float* __restrict__ out)
{
    const int b = blockIdx.x, t = threadIdx.x;
    __shared__ int   s_pos[C_];
    __shared__ float s_vm[C_ * W_];
    __shared__ float s_rq[128];
    __shared__ float s_vnorm[C_], s_knorm[R_];
    __shared__ float s_a[R_ * C_];
    __shared__ float s_p[R_ * C_];

    if (t == 0) {   // reduce 16 argmin partials, first-index tie-break
        float bv = amin_val[b * 16]; int bi = amin_idx[b * 16];
        for (int i = 1; i < 16; ++i) {
            float v = amin_val[b * 16 + i]; int id = amin_idx[b * 16 + i];
            if (v < bv || (v == bv && id < bi)) { bv = v; bi = id; }
        }
        s_pos[64] = bi;
    }
    if (t < 64)  s_pos[t] = ws_pos[b * C_ + t];
    if (t < 128) s_rq[t] = ws_rq[b * 128 + t];
    __syncthreads();

    for (int i = t; i < C_ * W_; i += 256) {
        int c = i >> 5, w = i & 31;
        int p = s_pos[c]; p = p < 0 ? 0 : (p > M_ - 1 ? M_ - 1 : p);
        s_vm[i] = memory[((size_t)b * M_ + p) * W_ + w];
    }
    __syncthreads();
    if (t < C_) {
        float s = 0.f;
        for (int w = 0; w < W_; ++w) { float v = s_vm[t * W_ + w]; s = fmaf(v, v, s); }
        s_vnorm[t] = sqrtf(s) + 1e-6f;
    } else if (t < C_ + R_) {
        int r = t - C_;
        float s = 0.f;
        for (int w = 0; w < W_; ++w) { float v = s_rq[r * W_ + w]; s = fmaf(v, v, s); }
        s_knorm[r] = sqrtf(s) + 1e-6f;
    }
    __syncthreads();
    for (int i = t; i < R_ * C_; i += 256) {
        int r = i / C_, c = i % C_;
        float s = 0.f;
        for (int w = 0; w < W_; ++w) s = fmaf(s_vm[c * W_ + w], s_rq[r * W_ + w], s);
        s_a[i] = s / (32.0f * s_vnorm[c] * s_knorm[r] + 1e-6f);
    }
    __syncthreads();
    if (t < R_) {
        float mx = -INFINITY;
        for (int c = 0; c < C_; ++c) mx = fmaxf(mx, s_a[t * C_ + c]);
        float sum = 0.f;
        for (int c = 0; c < C_; ++c) { float e = expf(s_a[t * C_ + c] - mx); s_p[t * C_ + c] = e; sum += e; }
        float inv = 1.f / sum;
        for (int c = 0; c < C_; ++c) s_p[t * C_ + c] *= inv;
    }
    __syncthreads();
    if (t < 128) {
        int r = t >> 5, w = t & 31;
        float s = 0.f;
        for (int c = 0; c < C_; ++c) s = fmaf(s_p[r * C_ + c], s_vm[c * W_ + w], s);
        out[((size_t)b * R_ + r) * W_ + w] = s;
    }
}

extern "C" void kernel_launch(void* const* d_in, const int* in_sizes, int n_in,
                              void* d_out, int out_size, void* d_ws, size_t ws_size,
                              hipStream_t stream)
{
    const float* xi            = (const float*)d_in[0];
    float*       memory        = (float*)d_in[1];        // updated in place; harness restores inputs
    const float* read_weights  = (const float*)d_in[2];
    const float* write_weights = (const float*)d_in[3];
    float*       usage         = (float*)d_in[4];        // updated in place
    const float* visible       = (const float*)d_in[5];
    const float* W_rq = (const float*)d_in[6];
    const float* b_rq = (const float*)d_in[7];
    const float* W_wv = (const float*)d_in[8];
    const float* b_wv = (const float*)d_in[9];
    const float* W_ig = (const float*)d_in[10];
    const float* b_ig = (const float*)d_in[11];
    const float* W_wg = (const float*)d_in[12];
    const float* b_wg = (const float*)d_in[13];
    const int*   read_pos = (const int*)d_in[14];
    const int*   timestep = (const int*)d_in[16];
    float* out = (float*)d_out;
    (void)in_sizes; (void)n_in; (void)out_size; (void)ws_size;

    // workspace layout (~34 MB)
    float* ws_rq    = (float*)d_ws;                  // 32*128 = 4096
    float* scores   = ws_rq + 4096;                  // 32*4*65536 = 8388608 floats (32 MB)
    float* amin_val = scores + 8388608;              // 32*16
    int*   amin_idx = (int*)(amin_val + 512);        // 32*16
    int*   ws_pos   = amin_idx + 512;                // 32*65

    k_prep<<<dim3(32), dim3(256), 0, stream>>>(xi, memory, read_weights, write_weights,
        usage, visible, W_rq, b_rq, W_wv, b_wv, W_ig, b_ig, W_wg, b_wg,
        read_pos, timestep, ws_rq);
    k_argmin<<<dim3(16, 32), dim3(256), 0, stream>>>(usage, amin_val, amin_idx);
    k_scores<<<dim3(64, 32), dim3(256), 0, stream>>>(memory, ws_rq, scores);
    k_sel<<<dim3(128), dim3(1024), 0, stream>>>(scores, ws_pos);
    k_final<<<dim3(32), dim3(256), 0, stream>>>(memory, ws_rq, amin_val, amin_idx, ws_pos, out);
}

// Round 3
// 501.385 us; speedup vs baseline: 2.1197x; 1.3836x over previous
//
#include <hip/hip_runtime.h>
#include <math.h>

#define B_  32
#define M_  65536
#define W_  32
#define R_  4
#define K_  16
#define C_  65
#define IN_ 256

// ---------------- kernel 1: small matmuls + gather/update/scatter (in-place) ----------------
__global__ __launch_bounds__(256) void k_prep(
    const float* __restrict__ xi, float* __restrict__ memory,
    const float* __restrict__ read_weights, const float* __restrict__ write_weights,
    float* __restrict__ usage, const float* __restrict__ visible,
    const float* __restrict__ W_rq, const float* __restrict__ b_rq,
    const float* __restrict__ W_wv, const float* __restrict__ b_wv,
    const float* __restrict__ W_ig, const float* __restrict__ b_ig,
    const float* __restrict__ W_wg, const float* __restrict__ b_wg,
    const int* __restrict__ read_pos, const int* __restrict__ timestep_p,
    float* __restrict__ ws_rq)
{
    const int b = blockIdx.x, t = threadIdx.x;
    __shared__ __align__(16) float s_xi[IN_];
    __shared__ float s_wv[W_];
    __shared__ float s_ig[C_];
    __shared__ float s_wg;
    __shared__ float s_ru[C_], s_rwg[C_], s_u[C_];
    __shared__ float s_I[C_], s_wwnew[C_];
    __shared__ int   s_rp[C_];
    __shared__ unsigned char s_wok[C_];
    __shared__ float s_minu;

    s_xi[t] = xi[b * IN_ + t];
    __syncthreads();

    if (t < 226) {
        const float* wrow; float bias;
        if (t < 128)      { wrow = W_rq + t * IN_;         bias = b_rq[t]; }
        else if (t < 160) { wrow = W_wv + (t - 128) * IN_; bias = b_wv[t - 128]; }
        else if (t < 225) { wrow = W_ig + (t - 160) * IN_; bias = b_ig[t - 160]; }
        else              { wrow = W_wg;                   bias = b_wg[0]; }
        float acc = 0.f;
        const float4* w4 = (const float4*)wrow;
        const float4* x4 = (const float4*)s_xi;
        #pragma unroll 4
        for (int q = 0; q < IN_ / 4; ++q) {
            float4 wv = w4[q]; float4 xv = x4[q];
            acc = fmaf(wv.x, xv.x, acc); acc = fmaf(wv.y, xv.y, acc);
            acc = fmaf(wv.z, xv.z, acc); acc = fmaf(wv.w, xv.w, acc);
        }
        acc += bias;
        if (t < 128)      ws_rq[b * 128 + t] = acc;
        else if (t < 160) s_wv[t - 128] = acc;
        else if (t < 225) s_ig[t - 160] = 1.f / (1.f + expf(-acc));
        else              s_wg = 1.f / (1.f + expf(-acc));
    }

    const int ts = timestep_p[0];
    if (t < C_) {
        int p = read_pos[b * C_ + t];
        s_rp[t] = p;
        float rwg = read_weights[(size_t)b * M_ + p];
        if (ts == 1) rwg += 1.0f;
        float wwg = write_weights[(size_t)b * M_ + p];
        s_rwg[t] = rwg;
        s_u[t]  = ((rwg + wwg) > 0.005f) ? 1.0f : 0.0f;
        s_ru[t] = usage[(size_t)b * M_ + p];
    }
    __syncthreads();
    if (t == 0) {
        float mn = s_ru[0];
        for (int c = 1; c < C_; ++c) mn = fminf(mn, s_ru[c]);
        s_minu = mn;
    }
    __syncthreads();
    if (t < C_) {
        float ru = s_ru[t];
        float I  = (ru == s_minu) ? 1.0f : 0.0f;
        float u  = s_u[t];
        float relnew = ((float)ts - ru) * u + ru * (1.0f - u);
        float ig = s_ig[t];
        float wwn = s_wg * (ig * s_rwg[t] + (1.0f - ig) * I);
        s_I[t] = I; s_wwnew[t] = wwn;
        usage[(size_t)b * M_ + s_rp[t]] = relnew;
        unsigned char ok = 1;
        for (int c2 = t + 1; c2 < C_; ++c2) if (s_rp[c2] == s_rp[t]) { ok = 0; break; }
        s_wok[t] = ok;
    }
    __syncthreads();
    for (int i = t; i < C_ * W_; i += 256) {
        int c = i >> 5, w = i & 31;
        if (s_wok[c]) {
            float v = visible[((size_t)b * C_ + c) * W_ + w] * (1.0f - s_I[c]) + s_wwnew[c] * s_wv[w];
            memory[((size_t)b * M_ + s_rp[c]) * W_ + w] = v;
        }
    }
}

// ---------------- kernel 2: argmin partials over updated usage ----------------
__global__ __launch_bounds__(256) void k_argmin(
    const float* __restrict__ usage, float* __restrict__ pval, int* __restrict__ pidx)
{
    const int b = blockIdx.y, chunk = blockIdx.x, t = threadIdx.x;
    const float* u = usage + (size_t)b * M_ + chunk * 4096;
    float bv = 3.4e38f; int bi = 0x7fffffff;
    #pragma unroll
    for (int i = t; i < 4096; i += 256) {      // per-thread indices ascend -> strict < keeps first
        float v = u[i];
        if (v < bv) { bv = v; bi = i; }
    }
    __shared__ float sv[256]; __shared__ int si[256];
    sv[t] = bv; si[t] = bi; __syncthreads();
    for (int s = 128; s > 0; s >>= 1) {
        if (t < s) {
            if (sv[t + s] < sv[t] || (sv[t + s] == sv[t] && si[t + s] < si[t])) {
                sv[t] = sv[t + s]; si[t] = si[t + s];
            }
        }
        __syncthreads();
    }
    if (t == 0) { pval[b * 16 + chunk] = sv[0]; pidx[b * 16 + chunk] = chunk * 4096 + si[0]; }
}

// ---------------- kernel 3: coalesced streaming scores (shuffle-reduced) ----------------
// grid (64, 32), 256 threads; block covers 1024 rows = 32768 elements contiguous
__global__ __launch_bounds__(256) void k_scores(
    const float* __restrict__ memory, const float* __restrict__ ws_rq,
    float* __restrict__ scores)
{
    const int b = blockIdx.y, t = threadIdx.x;
    __shared__ float s_rq[128];
    if (t < 128) s_rq[t] = ws_rq[b * 128 + t];
    __syncthreads();

    const int j = t & 7;                 // 8 lanes own one 32-float row
    float q[4][4];
    #pragma unroll
    for (int r = 0; r < 4; ++r)
        #pragma unroll
        for (int k = 0; k < 4; ++k) q[r][k] = s_rq[r * 32 + j * 4 + k];

    const int rowbase = blockIdx.x << 10;
    const float* src = memory + (size_t)b * (M_ * W_) + (size_t)rowbase * W_;
    const int rloc = t >> 3;             // row within a 32-row chunk

    #pragma unroll 4
    for (int i = 0; i < 32; ++i) {
        float4 v = *(const float4*)(src + i * 1024 + t * 4);
        float p0 = fmaf(v.w, q[0][3], fmaf(v.z, q[0][2], fmaf(v.y, q[0][1], v.x * q[0][0])));
        float p1 = fmaf(v.w, q[1][3], fmaf(v.z, q[1][2], fmaf(v.y, q[1][1], v.x * q[1][0])));
        float p2 = fmaf(v.w, q[2][3], fmaf(v.z, q[2][2], fmaf(v.y, q[2][1], v.x * q[2][0])));
        float p3 = fmaf(v.w, q[3][3], fmaf(v.z, q[3][2], fmaf(v.y, q[3][1], v.x * q[3][0])));
        #pragma unroll
        for (int m = 1; m <= 4; m <<= 1) {
            p0 += __shfl_xor(p0, m);
            p1 += __shfl_xor(p1, m);
            p2 += __shfl_xor(p2, m);
            p3 += __shfl_xor(p3, m);
        }
        if (j < 4) {
            float wv = (j == 0) ? p0 : (j == 1) ? p1 : (j == 2) ? p2 : p3;
            int row = rowbase + i * 32 + rloc;
            scores[((size_t)((b << 2) + j) << 16) + row] = wv;
        }
    }
}

// ---------------- kernel 4: exact top-16 per (b,r): top-2 sample -> tau -> compact -> select ----
__global__ __launch_bounds__(256) void k_sel(
    const float* __restrict__ scores, int* __restrict__ ws_pos)
{
    const int br = blockIdx.x, t = threadIdx.x;
    const float* sc = scores + ((size_t)br << 16);
    __shared__ float s_cand[512];
    __shared__ float c_val[2048];
    __shared__ int   c_idx[2048];
    __shared__ float s_wv[4]; __shared__ int s_wi[4], s_ws[4];
    __shared__ float s_tau;
    __shared__ int   s_cnt;
    __shared__ int   s_res[16];

    // phase A: per-thread branchless top-2 over 256 values (coalesced float4)
    float m1 = -INFINITY, m2 = -INFINITY;
    #pragma unroll 8
    for (int i = 0; i < 64; ++i) {
        float4 v = *(const float4*)(sc + i * 1024 + t * 4);
        m2 = fmaxf(m2, fminf(m1, v.x)); m1 = fmaxf(m1, v.x);
        m2 = fmaxf(m2, fminf(m1, v.y)); m1 = fmaxf(m1, v.y);
        m2 = fmaxf(m2, fminf(m1, v.z)); m1 = fmaxf(m1, v.z);
        m2 = fmaxf(m2, fminf(m1, v.w)); m1 = fmaxf(m1, v.w);
    }
    s_cand[t] = m1; s_cand[256 + t] = m2;
    if (t == 0) s_cnt = 0;
    __syncthreads();

    // phase B: tau = exact 16th largest of the 512 candidates (wave 0, shuffle-only).
    // tau <= true 16th-largest of all 65536 => {v >= tau} is a superset of the exact top-16.
    if (t < 64) {
        float h[8];
        #pragma unroll
        for (int k = 0; k < 8; ++k) h[k] = s_cand[t * 8 + k];
        float tau = -INFINITY;
        for (int k = 0; k < 16; ++k) {
            float bv = h[0]; int bs = 0;
            #pragma unroll
            for (int q = 1; q < 8; ++q) if (h[q] > bv) { bv = h[q]; bs = q; }
            int bid = t * 8 + bs;
            #pragma unroll
            for (int off = 32; off > 0; off >>= 1) {
                float ov = __shfl_xor(bv, off);
                int   ob = __shfl_xor(bid, off);
                if (ov > bv || (ov == bv && ob < bid)) { bv = ov; bid = ob; }
            }
            #pragma unroll
            for (int q = 0; q < 8; ++q) if (bid == t * 8 + q) h[q] = -INFINITY;
            tau = bv;
        }
        if (t == 0) s_tau = tau;
    }
    __syncthreads();

    // phase C: compact all v >= tau (scores are L3-resident; ~16-50 hits expected)
    const float tau = s_tau;
    #pragma unroll 8
    for (int i = 0; i < 64; ++i) {
        const int base = i * 1024 + t * 4;
        float4 v = *(const float4*)(sc + base);
        if (v.x >= tau) { int p = atomicAdd(&s_cnt, 1); if (p < 2048) { c_val[p] = v.x; c_idx[p] = base; } }
        if (v.y >= tau) { int p = atomicAdd(&s_cnt, 1); if (p < 2048) { c_val[p] = v.y; c_idx[p] = base + 1; } }
        if (v.z >= tau) { int p = atomicAdd(&s_cnt, 1); if (p < 2048) { c_val[p] = v.z; c_idx[p] = base + 2; } }
        if (v.w >= tau) { int p = atomicAdd(&s_cnt, 1); if (p < 2048) { c_val[p] = v.w; c_idx[p] = base + 3; } }
    }
    __syncthreads();
    int n = s_cnt; if (n > 2048) n = 2048;

    // phase D: 16 rounds of block argmax, (val desc, idx asc) tie-break = lax.top_k order
    const int lane = t & 63, wid = t >> 6;
    for (int k = 0; k < 16; ++k) {
        float bv = -INFINITY; int bi = 0x7fffffff, bs = 0;
        for (int p = t; p < n; p += 256) {
            float v = c_val[p]; int id = c_idx[p];
            if (v > bv || (v == bv && id < bi)) { bv = v; bi = id; bs = p; }
        }
        #pragma unroll
        for (int off = 32; off > 0; off >>= 1) {
            float ov = __shfl_xor(bv, off);
            int   oi = __shfl_xor(bi, off);
            int   os = __shfl_xor(bs, off);
            if (ov > bv || (ov == bv && oi < bi)) { bv = ov; bi = oi; bs = os; }
        }
        if (lane == 0) { s_wv[wid] = bv; s_wi[wid] = bi; s_ws[wid] = bs; }
        __syncthreads();
        if (t == 0) {
            float fv = s_wv[0]; int fi = s_wi[0], fs = s_ws[0];
            #pragma unroll
            for (int w2 = 1; w2 < 4; ++w2)
                if (s_wv[w2] > fv || (s_wv[w2] == fv && s_wi[w2] < fi)) { fv = s_wv[w2]; fi = s_wi[w2]; fs = s_ws[w2]; }
            s_res[k] = fi;
            c_val[fs] = -INFINITY;
        }
        __syncthreads();
    }
    if (t < 16) {
        int b = br >> 2, r = br & 3;
        ws_pos[b * C_ + r * 16 + t] = s_res[t];
    }
}

// ---------------- kernel 5: gather + cosine + softmax + weighted sum ----------------
__global__ __launch_bounds__(256) void k_final(
    const float* __restrict__ memory, const float* __restrict__ ws_rq,
    const float* __restrict__ amin_val, const int* __restrict__ amin_idx,
    const int* __restrict__ ws_pos, float* __restrict__ out)
{
    const int b = blockIdx.x, t = threadIdx.x;
    __shared__ int   s_pos[C_];
    __shared__ float s_vm[C_ * W_];
    __shared__ float s_rq[128];
    __shared__ float s_vnorm[C_], s_knorm[R_];
    __shared__ float s_a[R_ * C_];
    __shared__ float s_p[R_ * C_];

    if (t == 0) {   // reduce 16 argmin partials, first-index tie-break
        float bv = amin_val[b * 16]; int bi = amin_idx[b * 16];
        for (int i = 1; i < 16; ++i) {
            float v = amin_val[b * 16 + i]; int id = amin_idx[b * 16 + i];
            if (v < bv || (v == bv && id < bi)) { bv = v; bi = id; }
        }
        s_pos[64] = bi;
    }
    if (t < 64)  s_pos[t] = ws_pos[b * C_ + t];
    if (t < 128) s_rq[t] = ws_rq[b * 128 + t];
    __syncthreads();

    for (int i = t; i < C_ * W_; i += 256) {
        int c = i >> 5, w = i & 31;
        int p = s_pos[c]; p = p < 0 ? 0 : (p > M_ - 1 ? M_ - 1 : p);
        s_vm[i] = memory[((size_t)b * M_ + p) * W_ + w];
    }
    __syncthreads();
    if (t < C_) {
        float s = 0.f;
        for (int w = 0; w < W_; ++w) { float v = s_vm[t * W_ + w]; s = fmaf(v, v, s); }
        s_vnorm[t] = sqrtf(s) + 1e-6f;
    } else if (t < C_ + R_) {
        int r = t - C_;
        float s = 0.f;
        for (int w = 0; w < W_; ++w) { float v = s_rq[r * W_ + w]; s = fmaf(v, v, s); }
        s_knorm[r] = sqrtf(s) + 1e-6f;
    }
    __syncthreads();
    for (int i = t; i < R_ * C_; i += 256) {
        int r = i / C_, c = i % C_;
        float s = 0.f;
        for (int w = 0; w < W_; ++w) s = fmaf(s_vm[c * W_ + w], s_rq[r * W_ + w], s);
        s_a[i] = s / (32.0f * s_vnorm[c] * s_knorm[r] + 1e-6f);
    }
    __syncthreads();
    if (t < R_) {
        float mx = -INFINITY;
        for (int c = 0; c < C_; ++c) mx = fmaxf(mx, s_a[t * C_ + c]);
        float sum = 0.f;
        for (int c = 0; c < C_; ++c) { float e = expf(s_a[t * C_ + c] - mx); s_p[t * C_ + c] = e; sum += e; }
        float inv = 1.f / sum;
        for (int c = 0; c < C_; ++c) s_p[t * C_ + c] *= inv;
    }
    __syncthreads();
    if (t < 128) {
        int r = t >> 5, w = t & 31;
        float s = 0.f;
        for (int c = 0; c < C_; ++c) s = fmaf(s_p[r * C_ + c], s_vm[c * W_ + w], s);
        out[((size_t)b * R_ + r) * W_ + w] = s;
    }
}

extern "C" void kernel_launch(void* const* d_in, const int* in_sizes, int n_in,
                              void* d_out, int out_size, void* d_ws, size_t ws_size,
                              hipStream_t stream)
{
    const float* xi            = (const float*)d_in[0];
    float*       memory        = (float*)d_in[1];        // updated in place; harness restores inputs
    const float* read_weights  = (const float*)d_in[2];
    const float* write_weights = (const float*)d_in[3];
    float*       usage         = (float*)d_in[4];        // updated in place
    const float* visible       = (const float*)d_in[5];
    const float* W_rq = (const float*)d_in[6];
    const float* b_rq = (const float*)d_in[7];
    const float* W_wv = (const float*)d_in[8];
    const float* b_wv = (const float*)d_in[9];
    const float* W_ig = (const float*)d_in[10];
    const float* b_ig = (const float*)d_in[11];
    const float* W_wg = (const float*)d_in[12];
    const float* b_wg = (const float*)d_in[13];
    const int*   read_pos = (const int*)d_in[14];
    const int*   timestep = (const int*)d_in[16];
    float* out = (float*)d_out;
    (void)in_sizes; (void)n_in; (void)out_size; (void)ws_size;

    // workspace layout (~34 MB)
    float* ws_rq    = (float*)d_ws;                  // 32*128 = 4096
    float* scores   = ws_rq + 4096;                  // 32*4*65536 = 8388608 floats (32 MB)
    float* amin_val = scores + 8388608;              // 32*16
    int*   amin_idx = (int*)(amin_val + 512);        // 32*16
    int*   ws_pos   = amin_idx + 512;                // 32*65

    k_prep<<<dim3(32), dim3(256), 0, stream>>>(xi, memory, read_weights, write_weights,
        usage, visible, W_rq, b_rq, W_wv, b_wv, W_ig, b_ig, W_wg, b_wg,
        read_pos, timestep, ws_rq);
    k_argmin<<<dim3(16, 32), dim3(256), 0, stream>>>(usage, amin_val, amin_idx);
    k_scores<<<dim3(64, 32), dim3(256), 0, stream>>>(memory, ws_rq, scores);
    k_sel<<<dim3(128), dim3(256), 0, stream>>>(scores, ws_pos);
    k_final<<<dim3(32), dim3(256), 0, stream>>>(memory, ws_rq, amin_val, amin_idx, ws_pos, out);
}

// Round 4
// 490.065 us; speedup vs baseline: 2.1687x; 1.0231x over previous
//
#include <hip/hip_runtime.h>
#include <math.h>

#define B_  32
#define M_  65536
#define W_  32
#define R_  4
#define K_  16
#define C_  65
#define IN_ 256

// ---------------- kernel 1: small matmuls + gather/update/scatter (in-place) ----------------
__global__ __launch_bounds__(256) void k_prep(
    const float* __restrict__ xi, float* __restrict__ memory,
    const float* __restrict__ read_weights, const float* __restrict__ write_weights,
    float* __restrict__ usage, const float* __restrict__ visible,
    const float* __restrict__ W_rq, const float* __restrict__ b_rq,
    const float* __restrict__ W_wv, const float* __restrict__ b_wv,
    const float* __restrict__ W_ig, const float* __restrict__ b_ig,
    const float* __restrict__ W_wg, const float* __restrict__ b_wg,
    const int* __restrict__ read_pos, const int* __restrict__ timestep_p,
    float* __restrict__ ws_rq)
{
    const int b = blockIdx.x, t = threadIdx.x;
    __shared__ __align__(16) float s_xi[IN_];
    __shared__ float s_wv[W_];
    __shared__ float s_ig[C_];
    __shared__ float s_wg;
    __shared__ float s_ru[C_], s_rwg[C_], s_u[C_];
    __shared__ float s_I[C_], s_wwnew[C_];
    __shared__ int   s_rp[C_];
    __shared__ unsigned char s_wok[C_];
    __shared__ float s_minu;

    s_xi[t] = xi[b * IN_ + t];
    __syncthreads();

    if (t < 226) {
        const float* wrow; float bias;
        if (t < 128)      { wrow = W_rq + t * IN_;         bias = b_rq[t]; }
        else if (t < 160) { wrow = W_wv + (t - 128) * IN_; bias = b_wv[t - 128]; }
        else if (t < 225) { wrow = W_ig + (t - 160) * IN_; bias = b_ig[t - 160]; }
        else              { wrow = W_wg;                   bias = b_wg[0]; }
        float acc = 0.f;
        const float4* w4 = (const float4*)wrow;
        const float4* x4 = (const float4*)s_xi;
        #pragma unroll 4
        for (int q = 0; q < IN_ / 4; ++q) {
            float4 wv = w4[q]; float4 xv = x4[q];
            acc = fmaf(wv.x, xv.x, acc); acc = fmaf(wv.y, xv.y, acc);
            acc = fmaf(wv.z, xv.z, acc); acc = fmaf(wv.w, xv.w, acc);
        }
        acc += bias;
        if (t < 128)      ws_rq[b * 128 + t] = acc;
        else if (t < 160) s_wv[t - 128] = acc;
        else if (t < 225) s_ig[t - 160] = 1.f / (1.f + expf(-acc));
        else              s_wg = 1.f / (1.f + expf(-acc));
    }

    const int ts = timestep_p[0];
    if (t < C_) {
        int p = read_pos[b * C_ + t];
        s_rp[t] = p;
        float rwg = read_weights[(size_t)b * M_ + p];
        if (ts == 1) rwg += 1.0f;
        float wwg = write_weights[(size_t)b * M_ + p];
        s_rwg[t] = rwg;
        s_u[t]  = ((rwg + wwg) > 0.005f) ? 1.0f : 0.0f;
        s_ru[t] = usage[(size_t)b * M_ + p];
    }
    __syncthreads();
    if (t == 0) {
        float mn = s_ru[0];
        for (int c = 1; c < C_; ++c) mn = fminf(mn, s_ru[c]);
        s_minu = mn;
    }
    __syncthreads();
    if (t < C_) {
        float ru = s_ru[t];
        float I  = (ru == s_minu) ? 1.0f : 0.0f;
        float u  = s_u[t];
        float relnew = ((float)ts - ru) * u + ru * (1.0f - u);
        float ig = s_ig[t];
        float wwn = s_wg * (ig * s_rwg[t] + (1.0f - ig) * I);
        s_I[t] = I; s_wwnew[t] = wwn;
        usage[(size_t)b * M_ + s_rp[t]] = relnew;
        unsigned char ok = 1;
        for (int c2 = t + 1; c2 < C_; ++c2) if (s_rp[c2] == s_rp[t]) { ok = 0; break; }
        s_wok[t] = ok;
    }
    __syncthreads();
    for (int i = t; i < C_ * W_; i += 256) {
        int c = i >> 5, w = i & 31;
        if (s_wok[c]) {
            float v = visible[((size_t)b * C_ + c) * W_ + w] * (1.0f - s_I[c]) + s_wwnew[c] * s_wv[w];
            memory[((size_t)b * M_ + s_rp[c]) * W_ + w] = v;
        }
    }
}

// ---------------- kernel 2: streaming scores + per-lane top-2 cands + usage-argmin partials ----
// grid (64, 32), 256 threads; block covers 1024 rows (32 KB of a (b)-slice), contiguous.
__global__ __launch_bounds__(256) void k_scores(
    const float* __restrict__ memory, const float* __restrict__ ws_rq,
    const float* __restrict__ usage,
    float* __restrict__ scores, float* __restrict__ cand,
    float* __restrict__ pval, int* __restrict__ pidx)
{
    const int b = blockIdx.y, x = blockIdx.x, t = threadIdx.x;
    __shared__ float s_rq[128];
    __shared__ __align__(16) float s_sc[4][1032];   // +8 pad: conflict-free scatter, 16B-aligned rows
    if (t < 128) s_rq[t] = ws_rq[b * 128 + t];
    __syncthreads();

    const int j = t & 7;                 // 8 lanes own one 32-float row
    float q[4][4];
    #pragma unroll
    for (int r = 0; r < 4; ++r)
        #pragma unroll
        for (int k = 0; k < 4; ++k) q[r][k] = s_rq[r * 32 + j * 4 + k];

    const int rowbase = x << 10;
    const float* src = memory + (size_t)b * (M_ * W_) + (size_t)rowbase * W_;
    const int rloc = t >> 3;             // row within a 32-row chunk

    float m1 = -INFINITY, m2 = -INFINITY;
    #pragma unroll 4
    for (int i = 0; i < 32; ++i) {
        float4 v = *(const float4*)(src + i * 1024 + t * 4);
        float p0 = fmaf(v.w, q[0][3], fmaf(v.z, q[0][2], fmaf(v.y, q[0][1], v.x * q[0][0])));
        float p1 = fmaf(v.w, q[1][3], fmaf(v.z, q[1][2], fmaf(v.y, q[1][1], v.x * q[1][0])));
        float p2 = fmaf(v.w, q[2][3], fmaf(v.z, q[2][2], fmaf(v.y, q[2][1], v.x * q[2][0])));
        float p3 = fmaf(v.w, q[3][3], fmaf(v.z, q[3][2], fmaf(v.y, q[3][1], v.x * q[3][0])));
        #pragma unroll
        for (int m = 1; m <= 4; m <<= 1) {
            p0 += __shfl_xor(p0, m);
            p1 += __shfl_xor(p1, m);
            p2 += __shfl_xor(p2, m);
            p3 += __shfl_xor(p3, m);
        }
        if (j < 4) {
            float wv = (j == 0) ? p0 : (j == 1) ? p1 : (j == 2) ? p2 : p3;
            s_sc[j][i * 32 + rloc] = wv;
            m2 = fmaxf(m2, fminf(m1, wv)); m1 = fmaxf(m1, wv);   // branchless top-2 of this lane's 32 rows
        }
    }
    // per-lane top-2 candidates: 64 per (block, r); subset => tau from them is conservative
    if (j < 4) {
        float* cd = cand + ((size_t)((b << 2) + j) << 12) + (x << 6) + (rloc << 1);
        cd[0] = m1; cd[1] = m2;
    }
    __syncthreads();
    // coalesced score writes: 4 planes x 4 KB contiguous
    #pragma unroll
    for (int r = 0; r < 4; ++r) {
        float4 v = *(const float4*)&s_sc[r][t * 4];
        *(float4*)(scores + (((size_t)((b << 2) + r)) << 16) + rowbase + t * 4) = v;
    }
    // fused usage-argmin partial over usage[b][rowbase .. rowbase+1024)
    const float* u = usage + (size_t)b * M_ + rowbase;
    float bv = 3.4e38f; int bi = 0x7fffffff;
    #pragma unroll
    for (int i = t; i < 1024; i += 256) {   // per-thread indices ascend -> strict < keeps first
        float v = u[i];
        if (v < bv) { bv = v; bi = i; }
    }
    __syncthreads();                        // s_sc reuse as reduction scratch
    float* sv = s_sc[0]; int* si = (int*)s_sc[1];
    sv[t] = bv; si[t] = bi; __syncthreads();
    for (int s = 128; s > 0; s >>= 1) {
        if (t < s) {
            if (sv[t + s] < sv[t] || (sv[t + s] == sv[t] && si[t + s] < si[t])) {
                sv[t] = sv[t + s]; si[t] = si[t + s];
            }
        }
        __syncthreads();
    }
    if (t == 0) { pval[(b << 6) + x] = sv[0]; pidx[(b << 6) + x] = rowbase + si[0]; }
}

// ---------------- kernel 3: exact top-16 per (b,r): tau from cands -> compact -> select ----
__global__ __launch_bounds__(256) void k_sel(
    const float* __restrict__ scores, const float* __restrict__ cand,
    int* __restrict__ ws_pos)
{
    const int br = blockIdx.x, t = threadIdx.x;
    const float* sc = scores + ((size_t)br << 16);
    const float* cd = cand + ((size_t)br << 12);
    __shared__ float s_cand[512];
    __shared__ float c_val[2048];
    __shared__ int   c_idx[2048];
    __shared__ float s_wv[4]; __shared__ int s_wi[4], s_ws[4];
    __shared__ float s_tau;
    __shared__ int   s_cnt;
    __shared__ int   s_res[16];

    // phase A: per-thread branchless top-2 over the 4096 precomputed candidates
    float m1 = -INFINITY, m2 = -INFINITY;
    #pragma unroll
    for (int i = 0; i < 16; ++i) {
        float v = cd[i * 256 + t];
        m2 = fmaxf(m2, fminf(m1, v)); m1 = fmaxf(m1, v);
    }
    s_cand[t] = m1; s_cand[256 + t] = m2;
    if (t == 0) s_cnt = 0;
    __syncthreads();

    // phase B: tau = exact 16th largest of the 512 candidates (wave 0, shuffle-only).
    // candidates are a subset of all scores => tau <= true 16th-largest => superset guarantee.
    if (t < 64) {
        float h[8];
        #pragma unroll
        for (int k = 0; k < 8; ++k) h[k] = s_cand[t * 8 + k];
        float tau = -INFINITY;
        for (int k = 0; k < 16; ++k) {
            float bv = h[0]; int bs = 0;
            #pragma unroll
            for (int q = 1; q < 8; ++q) if (h[q] > bv) { bv = h[q]; bs = q; }
            int bid = t * 8 + bs;
            #pragma unroll
            for (int off = 32; off > 0; off >>= 1) {
                float ov = __shfl_xor(bv, off);
                int   ob = __shfl_xor(bid, off);
                if (ov > bv || (ov == bv && ob < bid)) { bv = ov; bid = ob; }
            }
            #pragma unroll
            for (int q = 0; q < 8; ++q) if (bid == t * 8 + q) h[q] = -INFINITY;
            tau = bv;
        }
        if (t == 0) s_tau = tau;
    }
    __syncthreads();

    // phase C: compact all v >= tau (scores are L2/L3-resident; ~20-150 hits expected)
    const float tau = s_tau;
    #pragma unroll 8
    for (int i = 0; i < 64; ++i) {
        const int base = i * 1024 + t * 4;
        float4 v = *(const float4*)(sc + base);
        if (v.x >= tau) { int p = atomicAdd(&s_cnt, 1); if (p < 2048) { c_val[p] = v.x; c_idx[p] = base; } }
        if (v.y >= tau) { int p = atomicAdd(&s_cnt, 1); if (p < 2048) { c_val[p] = v.y; c_idx[p] = base + 1; } }
        if (v.z >= tau) { int p = atomicAdd(&s_cnt, 1); if (p < 2048) { c_val[p] = v.z; c_idx[p] = base + 2; } }
        if (v.w >= tau) { int p = atomicAdd(&s_cnt, 1); if (p < 2048) { c_val[p] = v.w; c_idx[p] = base + 3; } }
    }
    __syncthreads();
    int n = s_cnt; if (n > 2048) n = 2048;

    // phase D: 16 rounds of block argmax, (val desc, idx asc) tie-break = lax.top_k order
    const int lane = t & 63, wid = t >> 6;
    for (int k = 0; k < 16; ++k) {
        float bv = -INFINITY; int bi = 0x7fffffff, bs = 0;
        for (int p = t; p < n; p += 256) {
            float v = c_val[p]; int id = c_idx[p];
            if (v > bv || (v == bv && id < bi)) { bv = v; bi = id; bs = p; }
        }
        #pragma unroll
        for (int off = 32; off > 0; off >>= 1) {
            float ov = __shfl_xor(bv, off);
            int   oi = __shfl_xor(bi, off);
            int   os = __shfl_xor(bs, off);
            if (ov > bv || (ov == bv && oi < bi)) { bv = ov; bi = oi; bs = os; }
        }
        if (lane == 0) { s_wv[wid] = bv; s_wi[wid] = bi; s_ws[wid] = bs; }
        __syncthreads();
        if (t == 0) {
            float fv = s_wv[0]; int fi = s_wi[0], fs = s_ws[0];
            #pragma unroll
            for (int w2 = 1; w2 < 4; ++w2)
                if (s_wv[w2] > fv || (s_wv[w2] == fv && s_wi[w2] < fi)) { fv = s_wv[w2]; fi = s_wi[w2]; fs = s_ws[w2]; }
            s_res[k] = fi;
            c_val[fs] = -INFINITY;
        }
        __syncthreads();
    }
    if (t < 16) {
        int b = br >> 2, r = br & 3;
        ws_pos[b * C_ + r * 16 + t] = s_res[t];
    }
}

// ---------------- kernel 4: gather + cosine + softmax + weighted sum ----------------
__global__ __launch_bounds__(256) void k_final(
    const float* __restrict__ memory, const float* __restrict__ ws_rq,
    const float* __restrict__ amin_val, const int* __restrict__ amin_idx,
    const int* __restrict__ ws_pos, float* __restrict__ out)
{
    const int b = blockIdx.x, t = threadIdx.x;
    __shared__ int   s_pos[C_];
    __shared__ float s_vm[C_ * W_];
    __shared__ float s_rq[128];
    __shared__ float s_vnorm[C_], s_knorm[R_];
    __shared__ float s_a[R_ * C_];
    __shared__ float s_p[R_ * C_];

    if (t < 64) {   // reduce 64 argmin partials in wave 0, first-index tie-break
        float bv = amin_val[(b << 6) + t]; int bi = amin_idx[(b << 6) + t];
        #pragma unroll
        for (int off = 32; off > 0; off >>= 1) {
            float ov = __shfl_down(bv, off);
            int   oi = __shfl_down(bi, off);
            if (ov < bv || (ov == bv && oi < bi)) { bv = ov; bi = oi; }
        }
        if (t == 0) s_pos[64] = bi;
    }
    if (t < 64)  s_pos[t] = ws_pos[b * C_ + t];
    if (t < 128) s_rq[t] = ws_rq[b * 128 + t];
    __syncthreads();

    for (int i = t; i < C_ * W_; i += 256) {
        int c = i >> 5, w = i & 31;
        int p = s_pos[c]; p = p < 0 ? 0 : (p > M_ - 1 ? M_ - 1 : p);
        s_vm[i] = memory[((size_t)b * M_ + p) * W_ + w];
    }
    __syncthreads();
    if (t < C_) {
        float s = 0.f;
        for (int w = 0; w < W_; ++w) { float v = s_vm[t * W_ + w]; s = fmaf(v, v, s); }
        s_vnorm[t] = sqrtf(s) + 1e-6f;
    } else if (t < C_ + R_) {
        int r = t - C_;
        float s = 0.f;
        for (int w = 0; w < W_; ++w) { float v = s_rq[r * W_ + w]; s = fmaf(v, v, s); }
        s_knorm[r] = sqrtf(s) + 1e-6f;
    }
    __syncthreads();
    for (int i = t; i < R_ * C_; i += 256) {
        int r = i / C_, c = i % C_;
        float s = 0.f;
        for (int w = 0; w < W_; ++w) s = fmaf(s_vm[c * W_ + w], s_rq[r * W_ + w], s);
        s_a[i] = s / (32.0f * s_vnorm[c] * s_knorm[r] + 1e-6f);
    }
    __syncthreads();
    if (t < R_) {
        float mx = -INFINITY;
        for (int c = 0; c < C_; ++c) mx = fmaxf(mx, s_a[t * C_ + c]);
        float sum = 0.f;
        for (int c = 0; c < C_; ++c) { float e = expf(s_a[t * C_ + c] - mx); s_p[t * C_ + c] = e; sum += e; }
        float inv = 1.f / sum;
        for (int c = 0; c < C_; ++c) s_p[t * C_ + c] *= inv;
    }
    __syncthreads();
    if (t < 128) {
        int r = t >> 5, w = t & 31;
        float s = 0.f;
        for (int c = 0; c < C_; ++c) s = fmaf(s_p[r * C_ + c], s_vm[c * W_ + w], s);
        out[((size_t)b * R_ + r) * W_ + w] = s;
    }
}

extern "C" void kernel_launch(void* const* d_in, const int* in_sizes, int n_in,
                              void* d_out, int out_size, void* d_ws, size_t ws_size,
                              hipStream_t stream)
{
    const float* xi            = (const float*)d_in[0];
    float*       memory        = (float*)d_in[1];        // updated in place; harness restores inputs
    const float* read_weights  = (const float*)d_in[2];
    const float* write_weights = (const float*)d_in[3];
    float*       usage         = (float*)d_in[4];        // updated in place
    const float* visible       = (const float*)d_in[5];
    const float* W_rq = (const float*)d_in[6];
    const float* b_rq = (const float*)d_in[7];
    const float* W_wv = (const float*)d_in[8];
    const float* b_wv = (const float*)d_in[9];
    const float* W_ig = (const float*)d_in[10];
    const float* b_ig = (const float*)d_in[11];
    const float* W_wg = (const float*)d_in[12];
    const float* b_wg = (const float*)d_in[13];
    const int*   read_pos = (const int*)d_in[14];
    const int*   timestep = (const int*)d_in[16];
    float* out = (float*)d_out;
    (void)in_sizes; (void)n_in; (void)out_size; (void)ws_size;

    // workspace layout (~36 MB)
    float* ws_rq    = (float*)d_ws;                  // 32*128 = 4096
    float* scores   = ws_rq + 4096;                  // 32*4*65536 = 8388608 floats (32 MB)
    float* cand     = scores + 8388608;              // 32*4*4096 = 524288 floats (2 MB)
    float* amin_val = cand + 524288;                 // 32*64
    int*   amin_idx = (int*)(amin_val + 2048);       // 32*64
    int*   ws_pos   = amin_idx + 2048;               // 32*65

    k_prep<<<dim3(32), dim3(256), 0, stream>>>(xi, memory, read_weights, write_weights,
        usage, visible, W_rq, b_rq, W_wv, b_wv, W_ig, b_ig, W_wg, b_wg,
        read_pos, timestep, ws_rq);
    k_scores<<<dim3(64, 32), dim3(256), 0, stream>>>(memory, ws_rq, usage, scores, cand,
        amin_val, amin_idx);
    k_sel<<<dim3(128), dim3(256), 0, stream>>>(scores, cand, ws_pos);
    k_final<<<dim3(32), dim3(256), 0, stream>>>(memory, ws_rq, amin_val, amin_idx, ws_pos, out);
}